// Round 1
// 232.462 us; speedup vs baseline: 1.0295x; 1.0295x over previous
//
#include <hip/hip_runtime.h>
#include <hip/hip_bf16.h>

#define EPSV 1e-5f

typedef __attribute__((ext_vector_type(8))) short short8;
typedef __attribute__((ext_vector_type(4))) float f32x4;
typedef __attribute__((ext_vector_type(2))) float f32x2;
typedef __attribute__((ext_vector_type(4))) unsigned u32x4;

#define LDSU32 __attribute__((address_space(3))) unsigned int
#define GLBU32 const __attribute__((address_space(1))) unsigned int

// ws layout: w2 (1,179,648 B) | st (2,048 B).  S is ELIMINATED (fused).
#define W2_BYTES 1179648ull

// w_deform (o, C_in, 3, 3) fp32 -> w2 bf16 [o][K], K = p*288 + k*32 + c
// where p = g*2+ch (8 phases), C_in = p*32 + c.  Also zero st.
__global__ __launch_bounds__(256) void wt2_kernel(const float* __restrict__ wd,
                                                  __hip_bfloat16* __restrict__ w2,
                                                  float* __restrict__ st) {
  int idx = blockIdx.x * 256 + threadIdx.x;   // o*2304 + p*288 + k*32 + c
  int c  = idx & 31;
  int r  = idx >> 5;          // o*72 + p*9 + k
  int k  = r % 9;
  int r2 = r / 9;             // o*8 + p
  int p  = r2 & 7;
  int o  = r2 >> 3;
  w2[idx] = __float2bfloat16(wd[(o * 256 + p * 32 + c) * 9 + k]);
  if (blockIdx.x < 2) st[blockIdx.x * 256 + threadIdx.x] = 0.f;
}

static __device__ __forceinline__ f32x2 unpk(unsigned u) {
  union { unsigned i; float f; } lo, hi;
  lo.i = u << 16;
  hi.i = u & 0xffff0000u;
  return (f32x2){lo.f, hi.f};
}

// Fused sample+GEMM: block = (b, 2-row band).  out[b][o][n] computed directly,
// B-tiles (128 px x 32 ch) produced in-register from an LDS x-window.
// 72 K-iters (8 phases x 9 taps, BK=32).  A dbuf via global_load_lds + counted
// vmcnt; x-window dbuf via chunked reg-staging (1 row/iter).
__global__ __launch_bounds__(512, 2) void fused_kernel(
    const float* __restrict__ x, const float* __restrict__ shp,
    const float* __restrict__ woff, const __hip_bfloat16* __restrict__ w2,
    float* __restrict__ out, float* __restrict__ st) {
  __shared__ __align__(16) unsigned short sX[2][8 * 64 * 32];  // 2 x 32 KB, slot-swizzled
  __shared__ __align__(16) unsigned short sA[2][256 * 32];     // 2 x 16 KB, linear
  __shared__ __align__(16) unsigned short sB[128 * 32];        // 8 KB, slot-swizzled
  __shared__ float sW[288];

  const int b    = blockIdx.x & 7;       // XCD swizzle: batch -> XCD (x slab L2-resident)
  const int band = blockIdx.x >> 3;      // 0..31
  const int h0   = band << 1;
  const int t    = threadIdx.x;

  // sampler ids: pixel n = hh*64+pxl, 8 channels per thread
  const int n   = t & 127;
  const int hh  = n >> 6;
  const int pxl = n & 63;
  const int cq2 = t >> 7;                // 0..3 (8-ch slot)
  const int h   = h0 + hh;

  // x-stage ids: 4 channels per thread, one row per chunk
  const int spx = t & 63;
  const int scq = t >> 6;                // 0..7 -> channels scq*4..+3 (wave-uniform)

  // mfma ids: 8 waves as 4(M) x 2(N), each 64x64
  const int wv = t >> 6, lane = t & 63;
  const int quad = lane >> 4, l15 = lane & 15;
  const int wm = wv & 3, wn = wv >> 2;

  const float* xb = x + ((size_t)b << 20);
  const unsigned short* w2b = (const unsigned short*)w2;

  if (t < 288) sW[t] = woff[t];

  float a0 = shp[((size_t)(b * 4 + 0) << 12) + (h << 6) + pxl];
  float a1 = shp[((size_t)(b * 4 + 1) << 12) + (h << 6) + pxl];
  float a2 = shp[((size_t)(b * 4 + 2) << 12) + (h << 6) + pxl];
  float a3 = shp[((size_t)(b * 4 + 3) << 12) + (h << 6) + pxl];

  // x-window LDS slot swizzle (16B slots, bank-balanced): slot' = slot ^ ((px>>1)&3)
  const int xwoff = (((scq >> 1) ^ ((spx >> 1) & 3)) << 3) + ((scq & 1) << 2);

  // ---- prologue: x slab for phase 0 ----
  {
    float v[8][4];
#pragma unroll
    for (int j = 0; j < 8; ++j) {
      const int grow = min(max(h0 - 3 + j, 0), 63);
      const float* ld = xb + ((size_t)(scq << 2) << 12) + (grow << 6) + spx;
      v[j][0] = ld[0]; v[j][1] = ld[4096]; v[j][2] = ld[8192]; v[j][3] = ld[12288];
    }
#pragma unroll
    for (int j = 0; j < 8; ++j) {
      __hip_bfloat162 pk0 = __float22bfloat162_rn(make_float2(v[j][0], v[j][1]));
      __hip_bfloat162 pk1 = __float22bfloat162_rn(make_float2(v[j][2], v[j][3]));
      *(uint2*)&sX[0][(((j << 6) + spx) << 5) + xwoff] =
          make_uint2(*(unsigned*)&pk0, *(unsigned*)&pk1);
    }
  }
  // ---- prologue: A slab it=0 ----
#pragma unroll
  for (int i = 0; i < 2; ++i) {
    const int f = (i << 9) + t;
    const int ao = f >> 2, sl = f & 3;
    __builtin_amdgcn_global_load_lds(
        (GLBU32*)(w2b + (size_t)ao * 2304 + (sl << 3)),
        (LDSU32*)(&sA[0][(i << 12) + (wv << 9)]), 16, 0, 0);
  }

  asm volatile("s_waitcnt lgkmcnt(0)" ::: "memory");
  asm volatile("s_barrier" ::: "memory");

  f32x4 acc[4][4];
#pragma unroll
  for (int mo = 0; mo < 4; ++mo)
#pragma unroll
    for (int np = 0; np < 4; ++np) acc[mo][np] = (f32x4){0.f, 0.f, 0.f, 0.f};

  float xr0 = 0.f, xr1 = 0.f, xr2 = 0.f, xr3 = 0.f;
  int phase = 0, k = 0;

  for (int it = 0; it < 72; ++it) {
    const int abuf = it & 1;
    const int xbuf = phase & 1;
    const int g = phase >> 1;

    // (a) commit x chunk k-1 (loaded last iter) into next-phase buffer
    if (phase < 7 && k >= 1) {
      __hip_bfloat162 pk0 = __float22bfloat162_rn(make_float2(xr0, xr1));
      __hip_bfloat162 pk1 = __float22bfloat162_rn(make_float2(xr2, xr3));
      *(uint2*)&sX[xbuf ^ 1][((((k - 1) << 6) + spx) << 5) + xwoff] =
          make_uint2(*(unsigned*)&pk0, *(unsigned*)&pk1);
    }
    // (b) issue x chunk k (row k) of phase+1 into regs
    if (phase < 7 && k <= 7) {
      const int grow = min(max(h0 - 3 + k, 0), 63);
      const float* ld = xb + ((size_t)(((phase + 1) << 5) + (scq << 2)) << 12) + (grow << 6) + spx;
      xr0 = ld[0]; xr1 = ld[4096]; xr2 = ld[8192]; xr3 = ld[12288];
    }
    // (c) issue A slab for it+1 (other buffer)
    if (it < 71) {
      const unsigned short* src = w2b + (size_t)(it + 1) * 32;
#pragma unroll
      for (int i = 0; i < 2; ++i) {
        const int f = (i << 9) + t;
        const int ao = f >> 2, sl = f & 3;
        __builtin_amdgcn_global_load_lds(
            (GLBU32*)(src + (size_t)ao * 2304 + (sl << 3)),
            (LDSU32*)(&sA[abuf ^ 1][(i << 12) + (wv << 9)]), 16, 0, 0);
      }
    }

    // (d) sampler: 8 channels for pixel (h,pxl), group g, tap k
    const float* wp = &sW[(g * 9 + k) << 3];
    float dy = wp[0]*a0 + wp[1]*a1 + wp[2]*a2 + wp[3]*a3;
    float dx = wp[4]*a0 + wp[5]*a1 + wp[6]*a2 + wp[7]*a3;
    float py  = dy + (float)(h + k / 3 - 1);
    float pxp = dx + (float)(pxl + k % 3 - 1);
    float y0f = floorf(py), x0f = floorf(pxp);
    float ly = py - y0f, lx = pxp - x0f;
    int y0 = (int)y0f, x0 = (int)x0f;
    float m_y0 = (y0 >=  0 && y0 <= 63) ? 1.f : 0.f;
    float m_y1 = (y0 >= -1 && y0 <= 62) ? 1.f : 0.f;
    float m_x0 = (x0 >=  0 && x0 <= 63) ? 1.f : 0.f;
    float m_x1 = (x0 >= -1 && x0 <= 62) ? 1.f : 0.f;
    float w00 = (1.f - ly) * (1.f - lx) * m_y0 * m_x0;
    float w01 = (1.f - ly) * lx         * m_y0 * m_x1;
    float w10 = ly         * (1.f - lx) * m_y1 * m_x0;
    float w11 = ly         * lx         * m_y1 * m_x1;
    int yc0 = min(max(y0, 0), 63),     yc1 = min(max(y0 + 1, 0), 63);
    int xc0 = min(max(x0, 0), 63),     xc1 = min(max(x0 + 1, 0), 63);
    int ry0 = min(max(yc0 - (h0 - 3), 0), 7);
    int ry1 = min(max(yc1 - (h0 - 3), 0), 7);
    const int s00 = (cq2 ^ ((xc0 >> 1) & 3)) << 3;
    const int s01 = (cq2 ^ ((xc1 >> 1) & 3)) << 3;
    const unsigned short* Xc = sX[xbuf];
    uint4 Au = *(const uint4*)&Xc[(((ry0 << 6) + xc0) << 5) + s00];
    uint4 Bu = *(const uint4*)&Xc[(((ry0 << 6) + xc1) << 5) + s01];
    uint4 Cu = *(const uint4*)&Xc[(((ry1 << 6) + xc0) << 5) + s00];
    uint4 Du = *(const uint4*)&Xc[(((ry1 << 6) + xc1) << 5) + s01];
    unsigned ua[4] = {Au.x, Au.y, Au.z, Au.w};
    unsigned ub[4] = {Bu.x, Bu.y, Bu.z, Bu.w};
    unsigned uc[4] = {Cu.x, Cu.y, Cu.z, Cu.w};
    unsigned ud[4] = {Du.x, Du.y, Du.z, Du.w};
    unsigned ov[4];
#pragma unroll
    for (int j = 0; j < 4; ++j) {
      f32x2 v = unpk(ua[j]) * w00 + unpk(ub[j]) * w01
              + unpk(uc[j]) * w10 + unpk(ud[j]) * w11;
      __hip_bfloat162 pk = __float22bfloat162_rn(make_float2(v.x, v.y));
      ov[j] = *(unsigned*)&pk;
    }

    // (e) counted vmcnt: retire A(this) only; keep this-iter issues in flight.
    //     Order-independent: this iter issued at most 6 VMEM ops (4 x + 2 A).
    if (it == 71) {
      asm volatile("s_waitcnt vmcnt(0)" ::: "memory");
    } else if (phase < 7 && k <= 7) {
      asm volatile("s_waitcnt vmcnt(6)" ::: "memory");
    } else {
      asm volatile("s_waitcnt vmcnt(2)" ::: "memory");
    }

    // (f) write B tile (slot-swizzled, bank-balanced)
    *(u32x4*)&sB[(n << 5) + ((cq2 ^ ((n >> 1) & 3)) << 3)] = (u32x4){ov[0], ov[1], ov[2], ov[3]};

    // (g) B + A(this) ready for everyone
    asm volatile("s_waitcnt lgkmcnt(0)" ::: "memory");
    asm volatile("s_barrier" ::: "memory");

    // (h) MFMA: 4x4 16x16 tiles per wave, K=32
    short8 af[4];
#pragma unroll
    for (int mo = 0; mo < 4; ++mo)
      af[mo] = *(const short8*)&sA[abuf][(((wm << 6) + (mo << 4) + l15) << 5) + (quad << 3)];
#pragma unroll
    for (int np = 0; np < 4; ++np) {
      const int row = (wn << 6) + (np << 4) + l15;
      short8 bf = *(const short8*)&sB[(row << 5) + ((quad ^ ((row >> 1) & 3)) << 3)];
#pragma unroll
      for (int mo = 0; mo < 4; ++mo)
        acc[mo][np] = __builtin_amdgcn_mfma_f32_16x16x32_bf16(af[mo], bf, acc[mo][np], 0, 0, 0);
    }

    // (j) done reading sB / sA[abuf]; safe to overwrite next iter
    asm volatile("s_barrier" ::: "memory");

    if (++k == 9) { k = 0; ++phase; }
  }

  // GN partial stats (group = 8 consecutive o)
#pragma unroll
  for (int mo = 0; mo < 4; ++mo) {
    float s = 0.f, q = 0.f;
#pragma unroll
    for (int np = 0; np < 4; ++np)
#pragma unroll
      for (int r = 0; r < 4; ++r) { float v = acc[mo][np][r]; s += v; q += v * v; }
#pragma unroll
    for (int m = 1; m < 16; m <<= 1) { s += __shfl_xor(s, m, 64); q += __shfl_xor(q, m, 64); }
    if (l15 == 0) {
      int gid = (b << 5) + (wm << 3) + (mo << 1) + (quad >> 1);
      atomicAdd(&st[gid], s);
      atomicAdd(&st[256 + gid], q);
    }
  }

  // C store: col(n)=l15, row(o)=quad*4+r per 16x16 block
  float* ob = out + ((size_t)((b << 8) + (wm << 6)) << 12) + (band << 7) + (wn << 6);
#pragma unroll
  for (int mo = 0; mo < 4; ++mo)
#pragma unroll
    for (int np = 0; np < 4; ++np)
#pragma unroll
      for (int r = 0; r < 4; ++r)
        ob[((size_t)((mo << 4) + (quad << 2) + r) << 12) + (np << 4) + l15] = acc[mo][np][r];
}

// Normalize + affine + ReLU from atomic sums (full-line nt store).
__global__ __launch_bounds__(256) void norm_kernel(float* __restrict__ o,
    const float* __restrict__ st, const float* __restrict__ gamma,
    const float* __restrict__ beta) {
  int idx = blockIdx.x * 256 + threadIdx.x;    // float4s: 2,097,152
  f32x4* p = (f32x4*)o;
  int c = (idx >> 10) & 255;
  int b = idx >> 18;
  int g = b * 32 + (c >> 3);
  const float invn = 1.f / 32768.f;
  float mu  = st[g] * invn;
  float var = st[256 + g] * invn - mu * mu;
  float ga = gamma[c] * rsqrtf(var + EPSV);
  float be = beta[c] - mu * ga;
  f32x4 v = p[idx];
  v.x = fmaxf(fmaf(v.x, ga, be), 0.f);
  v.y = fmaxf(fmaf(v.y, ga, be), 0.f);
  v.z = fmaxf(fmaf(v.z, ga, be), 0.f);
  v.w = fmaxf(fmaf(v.w, ga, be), 0.f);
  __builtin_nontemporal_store(v, &p[idx]);
}

extern "C" void kernel_launch(void* const* d_in, const int* in_sizes, int n_in,
                              void* d_out, int out_size, void* d_ws, size_t ws_size,
                              hipStream_t stream) {
  const float* x     = (const float*)d_in[0];
  const float* shp   = (const float*)d_in[1];
  const float* woff  = (const float*)d_in[2];
  const float* wdef  = (const float*)d_in[3];
  const float* gamma = (const float*)d_in[4];
  const float* beta  = (const float*)d_in[5];
  float* out = (float*)d_out;
  __hip_bfloat16* w2 = (__hip_bfloat16*)d_ws;
  float* st          = (float*)((char*)d_ws + W2_BYTES);

  hipLaunchKernelGGL(wt2_kernel,   dim3(2304), dim3(256), 0, stream, wdef, w2, st);
  hipLaunchKernelGGL(fused_kernel, dim3(256),  dim3(512), 0, stream, x, shp, woff, w2, out, st);
  hipLaunchKernelGGL(norm_kernel,  dim3(8192), dim3(256), 0, stream, out, st, gamma, beta);
}

// Round 2
// 187.305 us; speedup vs baseline: 1.2777x; 1.2411x over previous
//
#include <hip/hip_runtime.h>
#include <hip/hip_bf16.h>

#define EPSV 1e-5f

typedef __attribute__((ext_vector_type(8))) short short8;
typedef __attribute__((ext_vector_type(4))) float f32x4;
typedef __attribute__((ext_vector_type(2))) float f32x2;
typedef __attribute__((ext_vector_type(4))) unsigned u32x4;

// ws layout: w2 (1,179,648 B) | st (2,048 B)
#define W2_BYTES 1179648ull

// w_deform (o, C_in, 3, 3) fp32 -> w2 bf16 [o][K], K = p*288 + k*32 + c,
// C_in = p*32 + c (p = phase 0..7).  Also zero st.
__global__ __launch_bounds__(256) void wt2_kernel(const float* __restrict__ wd,
                                                  __hip_bfloat16* __restrict__ w2,
                                                  float* __restrict__ st) {
  int idx = blockIdx.x * 256 + threadIdx.x;   // o*2304 + p*288 + k*32 + c
  int c  = idx & 31;
  int r  = idx >> 5;          // o*72 + p*9 + k
  int k  = r % 9;
  int r2 = r / 9;             // o*8 + p
  int p  = r2 & 7;
  int o  = r2 >> 3;
  w2[idx] = __float2bfloat16(wd[(o * 256 + p * 32 + c) * 9 + k]);
  if (blockIdx.x < 2) st[blockIdx.x * 256 + threadIdx.x] = 0.f;
}

static __device__ __forceinline__ f32x2 unpk(unsigned u) {
  union { unsigned i; float f; } lo, hi;
  lo.i = u << 16;
  hi.i = u & 0xffff0000u;
  return (f32x2){lo.f, hi.f};
}

static __device__ __forceinline__ unsigned pkbf(float a, float b) {
  __hip_bfloat162 p = __float22bfloat162_rn(make_float2(a, b));
  return *(unsigned*)&p;
}

// Fused sample+GEMM with PRODUCER/CONSUMER wave specialization.
// Block = (b, 2-row band), 512 thr = 8 waves.
//   waves 0-3 (consumers): 64x128 output tile each; A direct global->reg
//     (w2 is L2-resident), B from LDS; 32 MFMA/iter/wave.
//   waves 4-7 (producers): bilinear-sample next B tile (16 ch/thread) into
//     sB[(it+1)&1]; stream next phase's x-window (T14 issue-early/commit-late).
// ONE raw s_barrier per iter; producer VALU overlaps consumer MFMA on each SIMD.
__global__ __launch_bounds__(512, 2) void fused_kernel(
    const float* __restrict__ x, const float* __restrict__ shp,
    const float* __restrict__ woff, const __hip_bfloat16* __restrict__ w2,
    float* __restrict__ out, float* __restrict__ st) {
  __shared__ __align__(16) unsigned short sX[2][8 * 64 * 32];  // 2 x 32 KB x-window
  __shared__ __align__(16) unsigned short sB[2][128 * 32];     // 2 x 8 KB B tiles
  __shared__ float sW[288];

  const int b    = blockIdx.x & 7;       // XCD swizzle: batch -> XCD
  const int band = blockIdx.x >> 3;      // 0..31
  const int h0   = band << 1;
  const int t    = threadIdx.x;
  const int wv   = t >> 6, lane = t & 63;
  const int quad = lane >> 4, l15 = lane & 15;

  const float* xb = x + ((size_t)b << 20);
  const unsigned short* w2b = (const unsigned short*)w2;

  if (t < 288) sW[t] = woff[t];

  if (wv < 4) {
    // ============================ CONSUMER ============================
    const int cw = wv;                       // M-stripe: rows cw*64..+63
    const unsigned short* aro =
        w2b + (size_t)((cw << 6) + l15) * 2304 + (quad << 3);

    f32x4 acc[4][8];
#pragma unroll
    for (int mo = 0; mo < 4; ++mo)
#pragma unroll
      for (int np = 0; np < 8; ++np) acc[mo][np] = (f32x4){0.f, 0.f, 0.f, 0.f};

    short8 afc[4];                           // A frags for tile `it` (prefetched)
#pragma unroll
    for (int mo = 0; mo < 4; ++mo)
      afc[mo] = *(const short8*)(aro + (size_t)(mo << 4) * 2304);

    asm volatile("s_waitcnt lgkmcnt(0)" ::: "memory");  // sW writes
    asm volatile("s_barrier" ::: "memory");             // B1: sX[0]+sW ready
    asm volatile("s_barrier" ::: "memory");             // B2: tile0 in sB[0]

    for (int it = 0; it < 72; ++it) {
      const unsigned short* Bc = sB[it & 1];
#pragma unroll
      for (int np = 0; np < 8; ++np) {
        const int row = (np << 4) + l15;
        short8 bf = *(const short8*)&Bc[(row << 5) + ((quad ^ ((row >> 1) & 3)) << 3)];
#pragma unroll
        for (int mo = 0; mo < 4; ++mo)
          acc[mo][np] = __builtin_amdgcn_mfma_f32_16x16x32_bf16(afc[mo], bf, acc[mo][np], 0, 0, 0);
      }
      // prefetch A for it+1 AFTER last use; wait lands at next iter's MFMA,
      // load stays in flight across the raw barrier (vmcnt untouched).
      if (it < 71) {
#pragma unroll
        for (int mo = 0; mo < 4; ++mo)
          afc[mo] = *(const short8*)(aro + (size_t)(mo << 4) * 2304 + (size_t)((it + 1) << 5));
      }
      asm volatile("s_barrier" ::: "memory");
    }

    // GN partial stats (group = 8 consecutive o)
#pragma unroll
    for (int mo = 0; mo < 4; ++mo) {
      float s = 0.f, q = 0.f;
#pragma unroll
      for (int np = 0; np < 8; ++np)
#pragma unroll
        for (int r = 0; r < 4; ++r) { float v = acc[mo][np][r]; s += v; q += v * v; }
#pragma unroll
      for (int m = 1; m < 16; m <<= 1) { s += __shfl_xor(s, m, 64); q += __shfl_xor(q, m, 64); }
      if (l15 == 0) {
        int gid = (b << 5) + (cw << 3) + (mo << 1) + (quad >> 1);
        atomicAdd(&st[gid], s);
        atomicAdd(&st[256 + gid], q);
      }
    }

    // C store: col(n)=l15, row(o)=quad*4+r per 16x16 block
    float* ob = out + (((size_t)((b << 8) + (cw << 6))) << 12) + (band << 7);
#pragma unroll
    for (int mo = 0; mo < 4; ++mo)
#pragma unroll
      for (int np = 0; np < 8; ++np)
#pragma unroll
        for (int r = 0; r < 4; ++r)
          ob[((size_t)((mo << 4) + (quad << 2) + r) << 12) + (np << 4) + l15] = acc[mo][np][r];
  } else {
    // ============================ PRODUCER ============================
    const int pid   = t - 256;               // 0..255
    const int n     = pid & 127;             // pixel within band (hh*64+pxl)
    const int chalf = pid >> 7;              // 0/1: channels chalf*16..+15
    const int pxl   = n & 63;
    const int h     = h0 + (n >> 6);
    const int spx   = pid & 63;              // x-stage: pixel
    const int sc8   = (pid >> 6) & 3;        // x-stage: 8-ch slot
    const int wslot = (sc8 ^ ((spx >> 1) & 3)) << 3;

    float a0 = shp[((size_t)(b * 4 + 0) << 12) + (h << 6) + pxl];
    float a1 = shp[((size_t)(b * 4 + 1) << 12) + (h << 6) + pxl];
    float a2 = shp[((size_t)(b * 4 + 2) << 12) + (h << 6) + pxl];
    float a3 = shp[((size_t)(b * 4 + 3) << 12) + (h << 6) + pxl];

    // ---- prologue: stage sX[0] (phase 0 window, rows h0-3..h0+4 clamped) ----
    {
      const float* xph = xb + ((size_t)(sc8 << 3) << 12) + spx;
#pragma unroll
      for (int j = 0; j < 8; ++j) {
        const int grow = min(max(h0 - 3 + j, 0), 63);
        float v[8];
#pragma unroll
        for (int jj = 0; jj < 8; ++jj) v[jj] = xph[(jj << 12) + (grow << 6)];
        *(u32x4*)&sX[0][(((j << 6) + spx) << 5) + wslot] =
            (u32x4){pkbf(v[0], v[1]), pkbf(v[2], v[3]), pkbf(v[4], v[5]), pkbf(v[6], v[7])};
      }
    }

    // sample tap tk of phase tp for this thread's pixel -> sB[buf]
    auto produce = [&](int tp, int tk, int buf) {
      const float* wp = &sW[(((tp >> 1) * 9 + tk)) << 3];
      float dy = wp[0]*a0 + wp[1]*a1 + wp[2]*a2 + wp[3]*a3;
      float dx = wp[4]*a0 + wp[5]*a1 + wp[6]*a2 + wp[7]*a3;
      float py  = dy + (float)(h + tk / 3 - 1);
      float pxp = dx + (float)(pxl + tk % 3 - 1);
      float y0f = floorf(py), x0f = floorf(pxp);
      float ly = py - y0f, lx = pxp - x0f;
      int y0 = (int)y0f, x0 = (int)x0f;
      float m_y0 = (y0 >=  0 && y0 <= 63) ? 1.f : 0.f;
      float m_y1 = (y0 >= -1 && y0 <= 62) ? 1.f : 0.f;
      float m_x0 = (x0 >=  0 && x0 <= 63) ? 1.f : 0.f;
      float m_x1 = (x0 >= -1 && x0 <= 62) ? 1.f : 0.f;
      float w00 = (1.f - ly) * (1.f - lx) * m_y0 * m_x0;
      float w01 = (1.f - ly) * lx         * m_y0 * m_x1;
      float w10 = ly         * (1.f - lx) * m_y1 * m_x0;
      float w11 = ly         * lx         * m_y1 * m_x1;
      int yc0 = min(max(y0, 0), 63),     yc1 = min(max(y0 + 1, 0), 63);
      int xc0 = min(max(x0, 0), 63),     xc1 = min(max(x0 + 1, 0), 63);
      int ry0 = min(max(yc0 - (h0 - 3), 0), 7);
      int ry1 = min(max(yc1 - (h0 - 3), 0), 7);
      const unsigned short* Xc = sX[tp & 1];
      const int s0 = chalf << 1;                       // logical slots s0, s0+1
      const int z0 = (xc0 >> 1) & 3, z1 = (xc1 >> 1) & 3;
      const int ba = ((ry0 << 6) + xc0) << 5, bb2 = ((ry0 << 6) + xc1) << 5;
      const int bc = ((ry1 << 6) + xc0) << 5, bd = ((ry1 << 6) + xc1) << 5;
      uint4 A0 = *(const uint4*)&Xc[ba  + ((s0 ^ z0) << 3)];
      uint4 A1 = *(const uint4*)&Xc[ba  + (((s0 + 1) ^ z0) << 3)];
      uint4 B0 = *(const uint4*)&Xc[bb2 + ((s0 ^ z1) << 3)];
      uint4 B1 = *(const uint4*)&Xc[bb2 + (((s0 + 1) ^ z1) << 3)];
      uint4 C0 = *(const uint4*)&Xc[bc  + ((s0 ^ z0) << 3)];
      uint4 C1 = *(const uint4*)&Xc[bc  + (((s0 + 1) ^ z0) << 3)];
      uint4 D0 = *(const uint4*)&Xc[bd  + ((s0 ^ z1) << 3)];
      uint4 D1 = *(const uint4*)&Xc[bd  + (((s0 + 1) ^ z1) << 3)];
      unsigned ua[8] = {A0.x, A0.y, A0.z, A0.w, A1.x, A1.y, A1.z, A1.w};
      unsigned ub[8] = {B0.x, B0.y, B0.z, B0.w, B1.x, B1.y, B1.z, B1.w};
      unsigned uc[8] = {C0.x, C0.y, C0.z, C0.w, C1.x, C1.y, C1.z, C1.w};
      unsigned ud[8] = {D0.x, D0.y, D0.z, D0.w, D1.x, D1.y, D1.z, D1.w};
      unsigned ov[8];
#pragma unroll
      for (int j = 0; j < 8; ++j) {
        f32x2 v = unpk(ua[j]) * w00 + unpk(ub[j]) * w01
                + unpk(uc[j]) * w10 + unpk(ud[j]) * w11;
        ov[j] = pkbf(v.x, v.y);
      }
      const int nb5 = n << 5;
      const int zn = (n >> 1) & 3;
      *(u32x4*)&sB[buf][nb5 + ((s0 ^ zn) << 3)]       = (u32x4){ov[0], ov[1], ov[2], ov[3]};
      *(u32x4*)&sB[buf][nb5 + (((s0 + 1) ^ zn) << 3)] = (u32x4){ov[4], ov[5], ov[6], ov[7]};
    };

    auto commit8 = [&](const float* v, int row, int nb) {
      *(u32x4*)&sX[nb][(((row << 6) + spx) << 5) + wslot] =
          (u32x4){pkbf(v[0], v[1]), pkbf(v[2], v[3]), pkbf(v[4], v[5]), pkbf(v[6], v[7])};
    };

    asm volatile("s_waitcnt lgkmcnt(0)" ::: "memory");  // sX[0] writes done
    asm volatile("s_barrier" ::: "memory");             // B1

    produce(0, 0, 0);                                   // tile 0 -> sB[0]
    asm volatile("s_waitcnt lgkmcnt(0)" ::: "memory");
    asm volatile("s_barrier" ::: "memory");             // B2

    float xrA[8], xrB[8];
    int k = 0, phase = 0;
    for (int it = 0; it < 72; ++it) {
      // ---- x-window streaming for phase+1 (T14 issue-early / commit-late) ----
      // k=0: issue rows 0,1.  k=1: commit r0,r1, issue r2.  k=2..6: commit rk,
      // issue r(k+1).  k=7: commit r7.  All committed before first read (k=8).
      if (phase < 7) {
        const float* xph = xb + ((size_t)(((phase + 1) << 5) + (sc8 << 3)) << 12) + spx;
        if (k == 0) {
          const int g0 = min(max(h0 - 3, 0), 63);
          const int g1 = min(max(h0 - 2, 0), 63);
#pragma unroll
          for (int jj = 0; jj < 8; ++jj) xrA[jj] = xph[(jj << 12) + (g0 << 6)];
#pragma unroll
          for (int jj = 0; jj < 8; ++jj) xrB[jj] = xph[(jj << 12) + (g1 << 6)];
        } else if (k <= 7) {
          const int nb = (phase + 1) & 1;
          commit8(xrA, (k == 1) ? 0 : k, nb);
          if (k == 1) commit8(xrB, 1, nb);
          if (k <= 6) {
            const int grow = min(max(h0 - 3 + k + 1, 0), 63);
#pragma unroll
            for (int jj = 0; jj < 8; ++jj) xrA[jj] = xph[(jj << 12) + (grow << 6)];
          }
        }
      }
      // ---- produce tile it+1 into sB[(it+1)&1] ----
      if (it < 71) {
        const int tk = (k == 8) ? 0 : k + 1;
        const int tp = (k == 8) ? phase + 1 : phase;
        produce(tp, tk, (it + 1) & 1);
      }
      asm volatile("s_waitcnt lgkmcnt(0)" ::: "memory");  // LDS writes visible
      asm volatile("s_barrier" ::: "memory");
      if (++k == 9) { k = 0; ++phase; }
    }
  }
}

// Normalize + affine + ReLU from atomic sums (full-line nt store).
__global__ __launch_bounds__(256) void norm_kernel(float* __restrict__ o,
    const float* __restrict__ st, const float* __restrict__ gamma,
    const float* __restrict__ beta) {
  int idx = blockIdx.x * 256 + threadIdx.x;    // float4s: 2,097,152
  f32x4* p = (f32x4*)o;
  int c = (idx >> 10) & 255;
  int b = idx >> 18;
  int g = b * 32 + (c >> 3);
  const float invn = 1.f / 32768.f;
  float mu  = st[g] * invn;
  float var = st[256 + g] * invn - mu * mu;
  float ga = gamma[c] * rsqrtf(var + EPSV);
  float be = beta[c] - mu * ga;
  f32x4 v = p[idx];
  v.x = fmaxf(fmaf(v.x, ga, be), 0.f);
  v.y = fmaxf(fmaf(v.y, ga, be), 0.f);
  v.z = fmaxf(fmaf(v.z, ga, be), 0.f);
  v.w = fmaxf(fmaf(v.w, ga, be), 0.f);
  __builtin_nontemporal_store(v, &p[idx]);
}

extern "C" void kernel_launch(void* const* d_in, const int* in_sizes, int n_in,
                              void* d_out, int out_size, void* d_ws, size_t ws_size,
                              hipStream_t stream) {
  const float* x     = (const float*)d_in[0];
  const float* shp   = (const float*)d_in[1];
  const float* woff  = (const float*)d_in[2];
  const float* wdef  = (const float*)d_in[3];
  const float* gamma = (const float*)d_in[4];
  const float* beta  = (const float*)d_in[5];
  float* out = (float*)d_out;
  __hip_bfloat16* w2 = (__hip_bfloat16*)d_ws;
  float* st          = (float*)((char*)d_ws + W2_BYTES);

  hipLaunchKernelGGL(wt2_kernel,   dim3(2304), dim3(256), 0, stream, wdef, w2, st);
  hipLaunchKernelGGL(fused_kernel, dim3(256),  dim3(512), 0, stream, x, shp, woff, w2, out, st);
  hipLaunchKernelGGL(norm_kernel,  dim3(8192), dim3(256), 0, stream, out, st, gamma, beta);
}